// Round 1
// baseline (825.377 us; speedup 1.0000x reference)
//
#include <hip/hip_runtime.h>
#include <math.h>

#define KN     20
#define DMEMC  256
#define DNC    128
#define DEC    128
#define DEMBC  128
#define NBINSC 300
#define MPB    4    // sources per block: wave w handles source b0+w

__device__ __forceinline__ float4 ld4(const float* p) {
    return *reinterpret_cast<const float4*>(p);
}

// acc += q.x*W0 + q.y*W1 + q.z*W2 + q.w*W3   (componentwise over 4 output dims)
#define ACC4(acc, q, W0, W1, W2, W3)                                                   \
    acc.x = fmaf(q.x, W0.x, acc.x); acc.x = fmaf(q.y, W1.x, acc.x);                    \
    acc.x = fmaf(q.z, W2.x, acc.x); acc.x = fmaf(q.w, W3.x, acc.x);                    \
    acc.y = fmaf(q.x, W0.y, acc.y); acc.y = fmaf(q.y, W1.y, acc.y);                    \
    acc.y = fmaf(q.z, W2.y, acc.y); acc.y = fmaf(q.w, W3.y, acc.y);                    \
    acc.z = fmaf(q.x, W0.z, acc.z); acc.z = fmaf(q.y, W1.z, acc.z);                    \
    acc.z = fmaf(q.z, W2.z, acc.z); acc.z = fmaf(q.w, W3.z, acc.z);                    \
    acc.w = fmaf(q.x, W0.w, acc.w); acc.w = fmaf(q.y, W1.w, acc.w);                    \
    acc.w = fmaf(q.z, W2.w, acc.w); acc.w = fmaf(q.w, W3.w, acc.w);

__global__ __launch_bounds__(256) void graph_emb_kernel(
    const float* __restrict__ node_features,   // [N, 128]
    const float* __restrict__ edge_features,   // [E, 128]
    const float* __restrict__ memory_,         // [N, 256]
    const float* __restrict__ interval_table,  // [300, 128]
    const float* __restrict__ bin_boundaries,  // [301]
    const float* __restrict__ time_w,          // [128]
    const float* __restrict__ time_b,          // [128]
    const float* __restrict__ W_agg,           // [256, 256]
    const float* __restrict__ timestamps,      // [B]
    const float* __restrict__ edge_times,      // [B, K]
    const float* __restrict__ intervals,       // [B]
    const float* __restrict__ nei_intervals,   // [B, K]
    const int*   __restrict__ source_nodes,    // [B]
    const int*   __restrict__ neighbors,       // [B, K]
    const int*   __restrict__ edge_idxs,       // [B, K]
    float* __restrict__ out, int B)
{
    __shared__ float s_bb[NBINSC + 1];
    __shared__ __align__(16) float s_feat[MPB][DMEMC];      // summed [ete|ef], pre-scaled 1/cnt
    __shared__ __align__(16) float s_res[MPB][DMEMC];       // src0 + mean neighbor emb
    __shared__ __align__(16) float s_part[4][MPB][DMEMC];   // phase-C partials per f-chunk
    __shared__ int s_bins[MPB][KN + 1];

    const int t  = threadIdx.x;
    const int w  = t >> 6;          // wave id = which source of the 4
    const int l  = t & 63;          // lane
    const int b0 = blockIdx.x * MPB;
    const int b  = b0 + w;

    for (int i = t; i <= NBINSC; i += 256) s_bb[i] = bin_boundaries[i];
    __syncthreads();

    // ---- bucketize: lanes 0..20 of each wave do 21 binary searches ----
    if (l <= KN && b < B) {
        const float x = (l == 0) ? intervals[b] : nei_intervals[b * KN + (l - 1)];
        int lo = 0, hi = NBINSC + 1;           // lower_bound over s_bb[0..300]
        while (lo < hi) {
            int mid = (lo + hi) >> 1;
            if (s_bb[mid] < x) lo = mid + 1; else hi = mid;
        }
        int idx = lo - 1;
        idx = idx < 0 ? 0 : (idx > NBINSC - 1 ? NBINSC - 1 : idx);
        s_bins[w][l] = idx;
    }
    __syncthreads();

    const int d0 = 4 * l;                      // this lane's 4 dims
    if (b < B) {
        // ---- source embedding ----
        const int src = __builtin_amdgcn_readfirstlane(source_nodes[b]);
        float4 v = ld4(memory_ + (long)src * DMEMC + d0);
        float4 w4, c4;
        float ts = 0.f;
        if (l < 32) {
            const float4 a = ld4(node_features + (long)src * DNC + d0);
            v.x += a.x; v.y += a.y; v.z += a.z; v.w += a.w;
            w4 = ld4(time_w + d0);
            c4 = ld4(time_b + d0);
            ts = timestamps[b];
        } else {
            const float4 a = ld4(interval_table + (long)s_bins[w][0] * DEMBC + (d0 - 128));
            v.x += a.x; v.y += a.y; v.z += a.z; v.w += a.w;
        }

        // ---- merged neighbor loop: memory+feat gather AND message feats ----
        float cnt = 0.f;
        float4 nb4 = make_float4(0.f, 0.f, 0.f, 0.f);
        float4 fs  = make_float4(0.f, 0.f, 0.f, 0.f);
        #pragma unroll
        for (int k = 0; k < KN; ++k) {
            const int raw = __builtin_amdgcn_readfirstlane(neighbors[b * KN + k]);
            const float msk = (raw != -1) ? 1.f : 0.f;
            const int nbc = raw & ~(raw >> 31);     // max(raw, 0): safe row when invalid
            cnt += msk;

            const float4 x = ld4(memory_ + (long)nbc * DMEMC + d0);
            float4 a, f;
            if (l < 32) {
                a = ld4(node_features + (long)nbc * DNC + d0);
                const float dlt = ts - edge_times[b * KN + k];
                f.x = __cosf(fmaf(dlt, w4.x, c4.x));
                f.y = __cosf(fmaf(dlt, w4.y, c4.y));
                f.z = __cosf(fmaf(dlt, w4.z, c4.z));
                f.w = __cosf(fmaf(dlt, w4.w, c4.w));
            } else {
                const int e0 = d0 - 128;
                a = ld4(interval_table + (long)s_bins[w][k + 1] * DEMBC + e0);
                int ei = __builtin_amdgcn_readfirstlane(edge_idxs[b * KN + k]);
                ei = ei & ~(ei >> 31);
                f = ld4(edge_features + (long)ei * DEC + e0);
            }
            nb4.x = fmaf(x.x + a.x, msk, nb4.x);
            nb4.y = fmaf(x.y + a.y, msk, nb4.y);
            nb4.z = fmaf(x.z + a.z, msk, nb4.z);
            nb4.w = fmaf(x.w + a.w, msk, nb4.w);
            fs.x  = fmaf(f.x, msk, fs.x);
            fs.y  = fmaf(f.y, msk, fs.y);
            fs.z  = fmaf(f.z, msk, fs.z);
            fs.w  = fmaf(f.w, msk, fs.w);
        }
        const float inv = 1.f / fmaxf(cnt, 1.f);
        float4 r;
        r.x = fmaf(nb4.x, inv, v.x);
        r.y = fmaf(nb4.y, inv, v.y);
        r.z = fmaf(nb4.z, inv, v.z);
        r.w = fmaf(nb4.w, inv, v.w);
        *reinterpret_cast<float4*>(&s_res[w][d0]) = r;
        fs.x *= inv; fs.y *= inv; fs.z *= inv; fs.w *= inv;
        *reinterpret_cast<float4*>(&s_feat[w][d0]) = fs;
    }
    __syncthreads();

    // ---- Phase C: wave w handles f-chunk [64w, 64w+64) for ALL 4 sources ----
    // Per 4-f group: 4 broadcast ds_read_b128 + 4 coalesced dwordx4 W loads + 64 FMA.
    // W_agg still read exactly once per block (256 KB, L2-resident).
    {
        const int f0 = w * 64;
        float4 acc0 = make_float4(0.f, 0.f, 0.f, 0.f);
        float4 acc1 = make_float4(0.f, 0.f, 0.f, 0.f);
        float4 acc2 = make_float4(0.f, 0.f, 0.f, 0.f);
        float4 acc3 = make_float4(0.f, 0.f, 0.f, 0.f);
        #pragma unroll 2
        for (int fg = 0; fg < 64; fg += 4) {
            const int f = f0 + fg;
            const float4 q0 = *reinterpret_cast<const float4*>(&s_feat[0][f]);
            const float4 q1 = *reinterpret_cast<const float4*>(&s_feat[1][f]);
            const float4 q2 = *reinterpret_cast<const float4*>(&s_feat[2][f]);
            const float4 q3 = *reinterpret_cast<const float4*>(&s_feat[3][f]);
            const float4 W0 = ld4(W_agg + (long)(f + 0) * DMEMC + d0);
            const float4 W1 = ld4(W_agg + (long)(f + 1) * DMEMC + d0);
            const float4 W2 = ld4(W_agg + (long)(f + 2) * DMEMC + d0);
            const float4 W3 = ld4(W_agg + (long)(f + 3) * DMEMC + d0);
            ACC4(acc0, q0, W0, W1, W2, W3);
            ACC4(acc1, q1, W0, W1, W2, W3);
            ACC4(acc2, q2, W0, W1, W2, W3);
            ACC4(acc3, q3, W0, W1, W2, W3);
        }
        *reinterpret_cast<float4*>(&s_part[w][0][d0]) = acc0;
        *reinterpret_cast<float4*>(&s_part[w][1][d0]) = acc1;
        *reinterpret_cast<float4*>(&s_part[w][2][d0]) = acc2;
        *reinterpret_cast<float4*>(&s_part[w][3][d0]) = acc3;
    }
    __syncthreads();

    // ---- final combine: thread t handles dim t of each source ----
    #pragma unroll
    for (int s = 0; s < MPB; ++s) {
        const int bb = b0 + s;
        if (bb < B) {
            out[(long)bb * DMEMC + t] = s_res[s][t]
                + s_part[0][s][t] + s_part[1][s][t]
                + s_part[2][s][t] + s_part[3][s][t];
        }
    }
}

extern "C" void kernel_launch(void* const* d_in, const int* in_sizes, int n_in,
                              void* d_out, int out_size, void* d_ws, size_t ws_size,
                              hipStream_t stream) {
    const float* node_features  = (const float*)d_in[0];
    const float* edge_features  = (const float*)d_in[1];
    const float* memory_        = (const float*)d_in[2];
    const float* interval_table = (const float*)d_in[3];
    const float* bin_boundaries = (const float*)d_in[4];
    const float* time_w         = (const float*)d_in[5];
    const float* time_b         = (const float*)d_in[6];
    const float* W_agg          = (const float*)d_in[7];
    const float* timestamps     = (const float*)d_in[8];
    const float* edge_times     = (const float*)d_in[9];
    const float* intervals      = (const float*)d_in[10];
    const float* nei_intervals  = (const float*)d_in[11];
    const int*   source_nodes   = (const int*)d_in[12];
    const int*   neighbors      = (const int*)d_in[13];
    const int*   edge_idxs      = (const int*)d_in[14];
    float* out = (float*)d_out;

    const int B = in_sizes[8];               // timestamps: [B]
    const int grid = (B + MPB - 1) / MPB;    // B=4096 -> 1024 blocks
    graph_emb_kernel<<<grid, 256, 0, stream>>>(
        node_features, edge_features, memory_, interval_table, bin_boundaries,
        time_w, time_b, W_agg, timestamps, edge_times, intervals, nei_intervals,
        source_nodes, neighbors, edge_idxs, out, B);
}

// Round 2
// 745.206 us; speedup vs baseline: 1.1076x; 1.1076x over previous
//
#include <hip/hip_runtime.h>
#include <math.h>

#define KN     20
#define HALF   10   // neighbors per wave
#define DMEMC  256
#define DNC    128
#define DEC    128
#define DEMBC  128
#define NBINSC 300
#define MPB    2    // sources per block; waves (2s+h): source s, half h

__device__ __forceinline__ float4 ld4(const float* p) {
    return *reinterpret_cast<const float4*>(p);
}

// acc += q.x*W0 + q.y*W1 + q.z*W2 + q.w*W3   (componentwise over 4 output dims)
#define ACC4(acc, q, W0, W1, W2, W3)                                                   \
    acc.x = fmaf(q.x, W0.x, acc.x); acc.x = fmaf(q.y, W1.x, acc.x);                    \
    acc.x = fmaf(q.z, W2.x, acc.x); acc.x = fmaf(q.w, W3.x, acc.x);                    \
    acc.y = fmaf(q.x, W0.y, acc.y); acc.y = fmaf(q.y, W1.y, acc.y);                    \
    acc.y = fmaf(q.z, W2.y, acc.y); acc.y = fmaf(q.w, W3.y, acc.y);                    \
    acc.z = fmaf(q.x, W0.z, acc.z); acc.z = fmaf(q.y, W1.z, acc.z);                    \
    acc.z = fmaf(q.z, W2.z, acc.z); acc.z = fmaf(q.w, W3.z, acc.z);                    \
    acc.w = fmaf(q.x, W0.w, acc.w); acc.w = fmaf(q.y, W1.w, acc.w);                    \
    acc.w = fmaf(q.z, W2.w, acc.w); acc.w = fmaf(q.w, W3.w, acc.w);

__global__ __launch_bounds__(256) void graph_emb_kernel(
    const float* __restrict__ node_features,   // [N, 128]
    const float* __restrict__ edge_features,   // [E, 128]
    const float* __restrict__ memory_,         // [N, 256]
    const float* __restrict__ interval_table,  // [300, 128]
    const float* __restrict__ bin_boundaries,  // [301]
    const float* __restrict__ time_w,          // [128]
    const float* __restrict__ time_b,          // [128]
    const float* __restrict__ W_agg,           // [256, 256]
    const float* __restrict__ timestamps,      // [B]
    const float* __restrict__ edge_times,      // [B, K]
    const float* __restrict__ intervals,       // [B]
    const float* __restrict__ nei_intervals,   // [B, K]
    const int*   __restrict__ source_nodes,    // [B]
    const int*   __restrict__ neighbors,       // [B, K]
    const int*   __restrict__ edge_idxs,       // [B, K]
    float* __restrict__ out, int B)
{
    __shared__ float s_bb[NBINSC + 1];
    __shared__ int   s_bins[MPB][KN + 1];
    __shared__ float s_cnt[MPB][2];
    __shared__ __align__(16) float s_src[MPB][DMEMC];        // src embedding (unscaled)
    __shared__ __align__(16) float s_gB[MPB][2][DMEMC];      // neighbor-emb partial sums
    __shared__ __align__(16) float s_gA[MPB][2][DMEMC];      // [ete|ef] partial sums
    __shared__ __align__(16) float s_part[4][MPB][DMEMC];    // phase-C partials per f-chunk

    const int t  = threadIdx.x;
    const int w  = t >> 6;          // wave id
    const int l  = t & 63;          // lane
    const int s  = w >> 1;          // source slot 0..1
    const int h  = w & 1;           // neighbor half 0..1
    const int b0 = blockIdx.x * MPB;
    const int b  = b0 + s;

    for (int i = t; i <= NBINSC; i += 256) s_bb[i] = bin_boundaries[i];
    __syncthreads();

    // ---- bucketize: lanes 0..20 of the h==0 wave of each source ----
    if (h == 0 && l <= KN && b < B) {
        const float x = (l == 0) ? intervals[b] : nei_intervals[b * KN + (l - 1)];
        int lo = 0, hi = NBINSC + 1;           // lower_bound over s_bb[0..300]
        while (lo < hi) {
            int mid = (lo + hi) >> 1;
            if (s_bb[mid] < x) lo = mid + 1; else hi = mid;
        }
        int idx = lo - 1;
        idx = idx < 0 ? 0 : (idx > NBINSC - 1 ? NBINSC - 1 : idx);
        s_bins[s][l] = idx;
    }
    __syncthreads();

    const int d0 = 4 * l;                      // this lane's 4 dims
    if (b < B) {
        const int kb0 = h * HALF;

        // preload this wave's 10 neighbor indices (batches the index loads)
        int nbk[HALF];
        #pragma unroll
        for (int k = 0; k < HALF; ++k) nbk[k] = neighbors[b * KN + kb0 + k];

        float cnt = 0.f;
        #pragma unroll
        for (int k = 0; k < HALF; ++k) cnt += (nbk[k] != -1) ? 1.f : 0.f;
        if (l == 0) s_cnt[s][h] = cnt;

        // ---- Phase B partial: sum of neighbor embeddings over this half ----
        float4 nb4 = make_float4(0.f, 0.f, 0.f, 0.f);
        #pragma unroll
        for (int k = 0; k < HALF; ++k) {
            const int nb = nbk[k];
            if (nb != -1) {
                const float4 x = ld4(memory_ + (long)nb * DMEMC + d0);
                float4 a;
                if (l < 32) a = ld4(node_features + (long)nb * DNC + d0);
                else        a = ld4(interval_table + (long)s_bins[s][kb0 + k + 1] * DEMBC + (d0 - 128));
                nb4.x += x.x + a.x; nb4.y += x.y + a.y;
                nb4.z += x.z + a.z; nb4.w += x.w + a.w;
            }
        }
        *reinterpret_cast<float4*>(&s_gB[s][h][d0]) = nb4;

        // ---- source embedding (h==0 wave only) ----
        if (h == 0) {
            const int src = source_nodes[b];
            float4 v = ld4(memory_ + (long)src * DMEMC + d0);
            float4 a;
            if (l < 32) a = ld4(node_features + (long)src * DNC + d0);
            else        a = ld4(interval_table + (long)s_bins[s][0] * DEMBC + (d0 - 128));
            v.x += a.x; v.y += a.y; v.z += a.z; v.w += a.w;
            *reinterpret_cast<float4*>(&s_src[s][d0]) = v;
        }

        // ---- Phase A partial: summed [ete | ef] over this half ----
        float4 fs = make_float4(0.f, 0.f, 0.f, 0.f);
        if (l < 32) {
            const float4 w4 = ld4(time_w + d0);
            const float4 c4 = ld4(time_b + d0);
            const float ts = timestamps[b];
            float et[HALF];
            #pragma unroll
            for (int k = 0; k < HALF; ++k) et[k] = edge_times[b * KN + kb0 + k];
            #pragma unroll
            for (int k = 0; k < HALF; ++k) {
                if (nbk[k] != -1) {
                    const float dlt = ts - et[k];
                    fs.x += __cosf(fmaf(dlt, w4.x, c4.x));
                    fs.y += __cosf(fmaf(dlt, w4.y, c4.y));
                    fs.z += __cosf(fmaf(dlt, w4.z, c4.z));
                    fs.w += __cosf(fmaf(dlt, w4.w, c4.w));
                }
            }
        } else {
            const int e0 = d0 - 128;
            int eik[HALF];
            #pragma unroll
            for (int k = 0; k < HALF; ++k) eik[k] = edge_idxs[b * KN + kb0 + k];
            #pragma unroll
            for (int k = 0; k < HALF; ++k) {
                if (nbk[k] != -1) {
                    const float4 a = ld4(edge_features + (long)eik[k] * DEC + e0);
                    fs.x += a.x; fs.y += a.y; fs.z += a.z; fs.w += a.w;
                }
            }
        }
        *reinterpret_cast<float4*>(&s_gA[s][h][d0]) = fs;
    }
    __syncthreads();

    // ---- Phase C: wave w handles f-chunk [64w, 64w+64) for both sources.
    //      q = (gA half0 + gA half1); 1/cnt folded in after the dot (linearity). ----
    {
        const int f0 = w * 64;
        float4 acc0 = make_float4(0.f, 0.f, 0.f, 0.f);
        float4 acc1 = make_float4(0.f, 0.f, 0.f, 0.f);
        #pragma unroll 2
        for (int fg = 0; fg < 64; fg += 4) {
            const int f = f0 + fg;
            const float4 qa0 = *reinterpret_cast<const float4*>(&s_gA[0][0][f]);
            const float4 qb0 = *reinterpret_cast<const float4*>(&s_gA[0][1][f]);
            const float4 qa1 = *reinterpret_cast<const float4*>(&s_gA[1][0][f]);
            const float4 qb1 = *reinterpret_cast<const float4*>(&s_gA[1][1][f]);
            const float4 q0 = make_float4(qa0.x + qb0.x, qa0.y + qb0.y,
                                          qa0.z + qb0.z, qa0.w + qb0.w);
            const float4 q1 = make_float4(qa1.x + qb1.x, qa1.y + qb1.y,
                                          qa1.z + qb1.z, qa1.w + qb1.w);
            const float4 W0 = ld4(W_agg + (long)(f + 0) * DMEMC + d0);
            const float4 W1 = ld4(W_agg + (long)(f + 1) * DMEMC + d0);
            const float4 W2 = ld4(W_agg + (long)(f + 2) * DMEMC + d0);
            const float4 W3 = ld4(W_agg + (long)(f + 3) * DMEMC + d0);
            ACC4(acc0, q0, W0, W1, W2, W3);
            ACC4(acc1, q1, W0, W1, W2, W3);
        }
        *reinterpret_cast<float4*>(&s_part[w][0][d0]) = acc0;
        *reinterpret_cast<float4*>(&s_part[w][1][d0]) = acc1;
    }
    __syncthreads();

    // ---- final combine: thread t handles dim t of each source ----
    #pragma unroll
    for (int ss = 0; ss < MPB; ++ss) {
        const int bb = b0 + ss;
        if (bb < B) {
            const float inv = 1.f / fmaxf(s_cnt[ss][0] + s_cnt[ss][1], 1.f);
            const float gB = s_gB[ss][0][t] + s_gB[ss][1][t];
            const float pa = s_part[0][ss][t] + s_part[1][ss][t]
                           + s_part[2][ss][t] + s_part[3][ss][t];
            out[(long)bb * DMEMC + t] = s_src[ss][t] + (gB + pa) * inv;
        }
    }
}

extern "C" void kernel_launch(void* const* d_in, const int* in_sizes, int n_in,
                              void* d_out, int out_size, void* d_ws, size_t ws_size,
                              hipStream_t stream) {
    const float* node_features  = (const float*)d_in[0];
    const float* edge_features  = (const float*)d_in[1];
    const float* memory_        = (const float*)d_in[2];
    const float* interval_table = (const float*)d_in[3];
    const float* bin_boundaries = (const float*)d_in[4];
    const float* time_w         = (const float*)d_in[5];
    const float* time_b         = (const float*)d_in[6];
    const float* W_agg          = (const float*)d_in[7];
    const float* timestamps     = (const float*)d_in[8];
    const float* edge_times     = (const float*)d_in[9];
    const float* intervals      = (const float*)d_in[10];
    const float* nei_intervals  = (const float*)d_in[11];
    const int*   source_nodes   = (const int*)d_in[12];
    const int*   neighbors      = (const int*)d_in[13];
    const int*   edge_idxs      = (const int*)d_in[14];
    float* out = (float*)d_out;

    const int B = in_sizes[8];               // timestamps: [B]
    const int grid = (B + MPB - 1) / MPB;    // B=4096 -> 2048 blocks
    graph_emb_kernel<<<grid, 256, 0, stream>>>(
        node_features, edge_features, memory_, interval_table, bin_boundaries,
        time_w, time_b, W_agg, timestamps, edge_times, intervals, nei_intervals,
        source_nodes, neighbors, edge_idxs, out, B);
}